// Round 11
// baseline (196.932 us; speedup 1.0000x reference)
//
#include <hip/hip_runtime.h>
#include <math.h>

#define BB 4
#define SS 2048
#define DD 1024
#define HH 16
#define HDD 64
#define NN (BB*SS)            // 8192 rows
#define WINDOWF 604800.0f     // 7 days
#define LOG2E 1.44269504088896340736f
#define SCALE2 (0.125f * LOG2E)   // 1/sqrt(64) * log2(e): scores in log2 domain

typedef __attribute__((ext_vector_type(8))) short bf16x8;
typedef __attribute__((ext_vector_type(4))) short bf16x4;
typedef __attribute__((ext_vector_type(4))) short s16x4;
typedef __attribute__((ext_vector_type(4))) float f32x4;

__device__ __forceinline__ unsigned short f2b(float f) {
    unsigned int x = __float_as_uint(f);
    unsigned int r = x + 0x7FFFu + ((x >> 16) & 1u);
    return (unsigned short)(r >> 16);
}

__device__ __forceinline__ unsigned int cvt_pk_bf16(float lo, float hi) {
    unsigned int r;
    asm("v_cvt_pk_bf16_f32 %0, %1, %2" : "=v"(r) : "v"(lo), "v"(hi));
    return r;
}

// async global->LDS, 16B per lane; LDS dest = wave-uniform base + lane*16
__device__ __forceinline__ void gload16(const unsigned short* g, unsigned short* l) {
    __builtin_amdgcn_global_load_lds(
        (const __attribute__((address_space(1))) unsigned int*)g,
        (__attribute__((address_space(3))) unsigned int*)l, 16, 0, 0);
}

// ---------------------------------------------------------------------------
// Fused f32->bf16 converts (x, Wq, Wk, Wv, Wo) + band_bounds, one launch.
// ---------------------------------------------------------------------------
__global__ __launch_bounds__(256)
void cvt_band(const float* __restrict__ x,
              const float* __restrict__ Wq, const float* __restrict__ Wk,
              const float* __restrict__ Wv, const float* __restrict__ Wo,
              const float* __restrict__ ts,
              unsigned short* __restrict__ xb,
              unsigned short* __restrict__ Wqb, unsigned short* __restrict__ Wkb,
              unsigned short* __restrict__ Wvb, unsigned short* __restrict__ Wob,
              int* __restrict__ lo, int* __restrict__ hi)
{
    const int g = blockIdx.x;
    const int tid = threadIdx.x;
    if (g < 12288) {
        const float* src; unsigned short* dst; int i;
        if (g < 8192) { src = x; dst = xb; i = g * 1024 + tid * 4; }
        else {
            const int wi = (g - 8192) >> 10;
            src = (wi == 0) ? Wq : (wi == 1) ? Wk : (wi == 2) ? Wv : Wo;
            dst = (wi == 0) ? Wqb : (wi == 1) ? Wkb : (wi == 2) ? Wvb : Wob;
            i = ((g - 8192) & 1023) * 1024 + tid * 4;
        }
        float4 v = *(const float4*)(src + i);
        s16x4 o;
        o[0] = (short)f2b(v.x); o[1] = (short)f2b(v.y);
        o[2] = (short)f2b(v.z); o[3] = (short)f2b(v.w);
        *(s16x4*)(dst + i) = o;
    } else {
        const int idx = (g - 12288) * 256 + tid;   // 0..8191
        const int b = idx / SS, q = idx % SS;
        const float* t = ts + (size_t)b * SS;
        float tq = t[q];
        float lot = tq - WINDOWF - 1.0f;
        float hit = tq + WINDOWF + 1.0f;
        int l = 0, r = q;
        while (l < r) { int m = (l + r) >> 1; if (t[m] < lot) l = m + 1; else r = m; }
        lo[idx] = l;
        int l2 = q, r2 = SS - 1;
        while (l2 < r2) { int m = (l2 + r2 + 1) >> 1; if (t[m] > hit) r2 = m - 1; else l2 = m; }
        hi[idx] = l2;
    }
}

// ---------------------------------------------------------------------------
// bf16 MFMA GEMM, m97 structure: BK=64, global_load_lds w=16 staging with
// pre-swizzled SOURCE (chunk ^= row&7) + swizzled ds_read, 2-barrier K-loop.
// Compile-time OUTMODE (R9 codegen): 0 = f32 row-major, 1 = bf16 row-major,
// 2 = bf16 transposed Vt layout [b][channel][s] (channel = h*64+d)
// ---------------------------------------------------------------------------
template<int OUTMODE>
__global__ __launch_bounds__(256)
void gemm_bf16(const unsigned short* __restrict__ A,
               const unsigned short* __restrict__ Bw,
               const float* __restrict__ bias,
               void* __restrict__ Y, int M, int N, int K, float alpha)
{
    constexpr int BM = 128, BN = 128, BK = 64;
    __shared__ unsigned short As[BM * BK];    // [row][64 elems], chunk-swizzled
    __shared__ unsigned short Bs[BN * BK];

    const int bm = blockIdx.x * BM;
    const int bn = blockIdx.y * BN;
    const int tid = threadIdx.x;
    const int wid = tid >> 6, l = tid & 63;
    const int wm = (wid >> 1) * 64, wn = (wid & 1) * 64;
    const int lr = l & 15, lg = l >> 4;

    const int srow = l >> 3;                       // 0..7 within 8-row group
    const int schunk = ((l & 7) ^ srow) * 8;       // elem offset in row

    f32x4 acc[4][4];
#pragma unroll
    for (int i = 0; i < 4; ++i)
#pragma unroll
        for (int j = 0; j < 4; ++j) acc[i][j] = (f32x4){0.f, 0.f, 0.f, 0.f};

    for (int k0 = 0; k0 < K; k0 += BK) {
#pragma unroll
        for (int i = 0; i < 4; ++i) {
            const int r0 = wid * 32 + i * 8;
            gload16(A  + (size_t)(bm + r0 + srow) * K + k0 + schunk, &As[r0 * BK]);
            gload16(Bw + (size_t)(bn + r0 + srow) * K + k0 + schunk, &Bs[r0 * BK]);
        }
        __syncthreads();                           // vmcnt drained -> LDS ready

#pragma unroll
        for (int ks = 0; ks < 2; ++ks) {
            bf16x8 af[4], bf[4];
#pragma unroll
            for (int am = 0; am < 4; ++am) {
                const int row = wm + am * 16 + lr;
                af[am] = *(const bf16x8*)&As[row * BK + (((ks * 4 + lg) ^ (row & 7)) * 8)];
            }
#pragma unroll
            for (int nf = 0; nf < 4; ++nf) {
                const int row = wn + nf * 16 + lr;
                bf[nf] = *(const bf16x8*)&Bs[row * BK + (((ks * 4 + lg) ^ (row & 7)) * 8)];
            }
#pragma unroll
            for (int am = 0; am < 4; ++am)
#pragma unroll
                for (int nf = 0; nf < 4; ++nf)
                    acc[am][nf] = __builtin_amdgcn_mfma_f32_16x16x32_bf16(
                        af[am], bf[nf], acc[am][nf], 0, 0, 0);
        }
        __syncthreads();                           // all reads done before restage
    }

    float bia[4];
#pragma unroll
    for (int nf = 0; nf < 4; ++nf) bia[nf] = bias[bn + wn + nf * 16 + lr];

#pragma unroll
    for (int am = 0; am < 4; ++am)
#pragma unroll
        for (int nf = 0; nf < 4; ++nf) {
            if (OUTMODE == 2) {
                int mbase = bm + wm + am * 16 + lg * 4;     // = b*SS + s_base
                int n = bn + wn + nf * 16 + lr;
                int bidx = mbase >> 11, sidx = mbase & (SS - 1);
                s16x4 o;
#pragma unroll
                for (int r = 0; r < 4; ++r)
                    o[r] = (short)f2b((acc[am][nf][r] + bia[nf]) * alpha);
                *(s16x4*)((unsigned short*)Y +
                          (((size_t)(bidx << 10) + n) << 11) + sidx) = o;
            } else {
#pragma unroll
                for (int r = 0; r < 4; ++r) {
                    float o = (acc[am][nf][r] + bia[nf]) * alpha;
                    size_t m = (size_t)(bm + wm + am * 16 + lg * 4 + r);
                    size_t n = (size_t)(bn + wn + nf * 16 + lr);
                    if (OUTMODE == 1) ((unsigned short*)Y)[m * N + n] = f2b(o);
                    else              ((float*)Y)[m * N + n] = o;
                }
            }
        }
}

// ---------------------------------------------------------------------------
// MFMA flash attention (R10 structure, kept): 64q tiles, dbuf gload_lds,
// ROTATION swizzle (slot = (chunk + row) & 7) on staging source and both
// read sites, defer-max, swapped QK, permuted-k PV, max3 reduce tree.
// ---------------------------------------------------------------------------
__global__ __launch_bounds__(256)
void attn_mfma(const unsigned short* __restrict__ Qb, const unsigned short* __restrict__ Kb,
               const unsigned short* __restrict__ Vt, const float* __restrict__ Tg,
               const int* __restrict__ lo, const int* __restrict__ hi,
               unsigned short* __restrict__ Ab)
{
    __shared__ unsigned short Ks[2][64 * 64];   // [key][dim], rotation-swizzled
    __shared__ unsigned short Vs[2][64 * 64];   // [dim][key], rotation-swizzled

    // XCD-aware decode: each XCD owns 8 (b,h) pairs; 32 q-tiles each.
    const int blk = blockIdx.x;
    const int xcd = blk & 7;
    const int idx = blk >> 3;              // 0..255
    const int bh  = xcd * 8 + (idx >> 5);
    const int qt  = idx & 31;
    const int b = bh >> 4, h = bh & 15;

    const int tid = threadIdx.x;
    const int wid = tid >> 6, l = tid & 63;
    const int lr = l & 15, lg = l >> 4;
    const int q0w = qt * 64 + wid * 16;

    const size_t qrow = (size_t)(b * SS + q0w + lr);
    const bf16x8 qf0 = *(const bf16x8*)(Qb + qrow * DD + h * HDD + lg * 8);
    const bf16x8 qf1 = *(const bf16x8*)(Qb + qrow * DD + h * HDD + 32 + lg * 8);

    const float* tb = Tg + (size_t)b * SS;
    const float tq = tb[q0w + lr];
    const float tq_min = tb[qt * 64];
    const float tq_max = tb[qt * 64 + 63];

    const int t0 = lo[b * SS + qt * 64] >> 6;
    const int t1 = hi[b * SS + qt * 64 + 63] >> 6;

    const unsigned short* Kbh = Kb + (size_t)b * SS * DD + h * HDD;
    const unsigned short* Vth = Vt + ((size_t)(b * 1024 + h * HDD)) * SS;

    // staging lane map: slot p = l&7 holds chunk c = (p - row) & 7
    const int srow = l >> 3;
    const int schunk = (((l & 7) - srow) & 7) * 8;

    // persistent staging pointers (advance by constant per tile)
    const unsigned short* kg0 = Kbh + (size_t)(t0 * 64 + wid * 16 + srow) * DD + schunk;
    const unsigned short* kg1 = kg0 + 8 * DD;
    const unsigned short* vg0 = Vth + (size_t)(wid * 16 + srow) * SS + t0 * 64 + schunk;
    const unsigned short* vg1 = vg0 + 8 * SS;

    // loop-invariant read offsets (elems), rotation p = (chunk + row) & 7
    const int ka_off = lr * 64 + (((lg + lr) & 7) << 3);     // QK row lr, chunk lg
    const int c0 = lg >> 1, h4 = (lg & 1) * 4;               // PV row lr (mod16)
    const int pv0 = lr * 64 + (((c0 + 0 + lr) & 7) << 3) + h4;
    const int pv1 = lr * 64 + (((c0 + 2 + lr) & 7) << 3) + h4;
    const int pv2 = lr * 64 + (((c0 + 4 + lr) & 7) << 3) + h4;
    const int pv3 = lr * 64 + (((c0 + 6 + lr) & 7) << 3) + h4;

    unsigned short *Kc = &Ks[0][0], *Kn = &Ks[1][0];
    unsigned short *Vc = &Vs[0][0], *Vn = &Vs[1][0];

    float m_ = -1e30f, l_ = 0.f;
    f32x4 o_[4];
#pragma unroll
    for (int df = 0; df < 4; ++df) o_[df] = (f32x4){0.f, 0.f, 0.f, 0.f};

    // prologue: stage tile t0 into buffer 0
    gload16(kg0, Kc + wid * 1024);
    gload16(kg1, Kc + wid * 1024 + 512);
    gload16(vg0, Vc + wid * 1024);
    gload16(vg1, Vc + wid * 1024 + 512);
    kg0 += 64 * DD; kg1 += 64 * DD; vg0 += 64; vg1 += 64;
    __syncthreads();

    for (int t = t0; t <= t1; ++t) {
        const int kk0 = t * 64;

        // ---- issue next tile's staging into the other buffer ----
        if (t < t1) {
            gload16(kg0, Kn + wid * 1024);
            gload16(kg1, Kn + wid * 1024 + 512);
            gload16(vg0, Vn + wid * 1024);
            gload16(vg1, Vn + wid * 1024 + 512);
            kg0 += 64 * DD; kg1 += 64 * DD; vg0 += 64; vg1 += 64;
        }

        // ---- QK^T from LDS ----
        f32x4 s[4];
        __builtin_amdgcn_s_setprio(1);
#pragma unroll
        for (int kf = 0; kf < 4; ++kf) {
            bf16x8 ka0 = *(const bf16x8*)(Kc + kf * 1024 + ka_off);
            bf16x8 ka1 = *(const bf16x8*)(Kc + kf * 1024 + (ka_off ^ 32));
            f32x4 z = (f32x4){0.f, 0.f, 0.f, 0.f};
            z = __builtin_amdgcn_mfma_f32_16x16x32_bf16(ka0, qf0, z, 0, 0, 0);
            z = __builtin_amdgcn_mfma_f32_16x16x32_bf16(ka1, qf1, z, 0, 0, 0);
            s[kf] = z;
        }
        __builtin_amdgcn_s_setprio(0);

        // ---- exact mask only on boundary tiles ----
        const bool needmask = !((tq_max - tb[kk0] <= WINDOWF - 4.0f) &&
                                (tb[kk0 + 63] - tq_min <= WINDOWF - 4.0f));
        if (needmask) {
#pragma unroll
            for (int kf = 0; kf < 4; ++kf) {
                float4 tk4 = *(const float4*)(tb + kk0 + kf * 16 + lg * 4);
                if (!(fabsf(tq - tk4.x) <= WINDOWF)) s[kf][0] = -INFINITY;
                if (!(fabsf(tq - tk4.y) <= WINDOWF)) s[kf][1] = -INFINITY;
                if (!(fabsf(tq - tk4.z) <= WINDOWF)) s[kf][2] = -INFINITY;
                if (!(fabsf(tq - tk4.w) <= WINDOWF)) s[kf][3] = -INFINITY;
            }
        }

        // ---- online softmax with defer-max (max via max3 tree) ----
        float t1_ = fmaxf(fmaxf(s[0][0], s[0][1]), s[0][2]);
        float t2_ = fmaxf(fmaxf(s[0][3], s[1][0]), s[1][1]);
        float t3_ = fmaxf(fmaxf(s[1][2], s[1][3]), s[2][0]);
        float t4_ = fmaxf(fmaxf(s[2][1], s[2][2]), s[2][3]);
        float t5_ = fmaxf(fmaxf(s[3][0], s[3][1]), s[3][2]);
        float mt = fmaxf(fmaxf(fmaxf(t1_, t2_), fmaxf(t3_, t4_)),
                         fmaxf(t5_, s[3][3]));
        mt = fmaxf(mt, __shfl_xor(mt, 16));
        mt = fmaxf(mt, __shfl_xor(mt, 32));
        if (!__all(mt <= m_ + 8.0f)) {
            const float mn = fmaxf(m_, mt);
            const float f_ = __builtin_amdgcn_exp2f(m_ - mn);
            l_ *= f_;
#pragma unroll
            for (int df = 0; df < 4; ++df)
#pragma unroll
                for (int r = 0; r < 4; ++r) o_[df][r] *= f_;
            m_ = mn;
        }
        float rs = 0.f;
#pragma unroll
        for (int kf = 0; kf < 4; ++kf)
#pragma unroll
            for (int r = 0; r < 4; ++r) {
                float p = __builtin_amdgcn_exp2f(s[kf][r] - m_);
                s[kf][r] = p;
                rs += p;
            }
        rs += __shfl_xor(rs, 16);
        rs += __shfl_xor(rs, 32);
        l_ += rs;

        // ---- P^T -> packed bf16 (in-register) ----
        union { unsigned int u[4]; bf16x8 v; } pb[2];
#pragma unroll
        for (int c = 0; c < 2; ++c) {
            pb[c].u[0] = cvt_pk_bf16(s[2 * c][0],     s[2 * c][1]);
            pb[c].u[1] = cvt_pk_bf16(s[2 * c][2],     s[2 * c][3]);
            pb[c].u[2] = cvt_pk_bf16(s[2 * c + 1][0], s[2 * c + 1][1]);
            pb[c].u[3] = cvt_pk_bf16(s[2 * c + 1][2], s[2 * c + 1][3]);
        }

        // ---- O^T += V^T . P^T from LDS ----
        __builtin_amdgcn_s_setprio(1);
#pragma unroll
        for (int df = 0; df < 4; ++df) {
            const int base = df * 1024;
            union { bf16x4 hh[2]; bf16x8 v; } va0, va1;
            va0.hh[0] = *(const bf16x4*)(Vc + base + pv0);
            va0.hh[1] = *(const bf16x4*)(Vc + base + pv1);
            va1.hh[0] = *(const bf16x4*)(Vc + base + pv2);
            va1.hh[1] = *(const bf16x4*)(Vc + base + pv3);
            o_[df] = __builtin_amdgcn_mfma_f32_16x16x32_bf16(va0.v, pb[0].v, o_[df], 0, 0, 0);
            o_[df] = __builtin_amdgcn_mfma_f32_16x16x32_bf16(va1.v, pb[1].v, o_[df], 0, 0, 0);
        }
        __builtin_amdgcn_s_setprio(0);

        __syncthreads();     // drains staging vmcnt; all reads of cur done
        unsigned short* tk = Kc; Kc = Kn; Kn = tk;
        unsigned short* tv = Vc; Vc = Vn; Vn = tv;
    }

    // finalize: attended[q][d] = O^T / l, packed 8B stores
    const float inv = 1.f / l_;
#pragma unroll
    for (int df = 0; df < 4; ++df) {
        s16x4 o;
#pragma unroll
        for (int r = 0; r < 4; ++r) o[r] = (short)f2b(o_[df][r] * inv);
        *(s16x4*)(Ab + qrow * DD + h * HDD + df * 16 + lg * 4) = o;
    }
}

// ---------------------------------------------------------------------------
// change_scores[n] = out[n,:] . Wc + bc   (one wave per row)
// ---------------------------------------------------------------------------
__global__ __launch_bounds__(256)
void change_kernel(const float* __restrict__ out, const float* __restrict__ Wc,
                   const float* __restrict__ bc, float* __restrict__ cs)
{
    int row = blockIdx.x * 4 + (threadIdx.x >> 6);
    int lane = threadIdx.x & 63;
    const float* o = out + (size_t)row * DD;
    float sum = 0.f;
#pragma unroll
    for (int k = 0; k < DD / 256; ++k) {
        int c = lane * 4 + k * 256;
        float4 v = *(const float4*)(o + c);
        float4 w = *(const float4*)(Wc + c);
        sum += v.x * w.x + v.y * w.y + v.z * w.z + v.w * w.w;
    }
#pragma unroll
    for (int off = 1; off < 64; off <<= 1) sum += __shfl_xor(sum, off);
    if (lane == 0) cs[row] = sum + bc[0];
}

// ---------------------------------------------------------------------------
extern "C" void kernel_launch(void* const* d_in, const int* in_sizes, int n_in,
                              void* d_out, int out_size, void* d_ws, size_t ws_size,
                              hipStream_t stream)
{
    (void)in_sizes; (void)n_in; (void)out_size; (void)ws_size;
    const float* x  = (const float*)d_in[0];
    const float* ts = (const float*)d_in[1];
    const float* Wq = (const float*)d_in[2];
    const float* bq = (const float*)d_in[3];
    const float* Wk = (const float*)d_in[4];
    const float* bk = (const float*)d_in[5];
    const float* Wv = (const float*)d_in[6];
    const float* bv = (const float*)d_in[7];
    const float* Wo = (const float*)d_in[8];
    const float* bo = (const float*)d_in[9];
    const float* Wc = (const float*)d_in[10];
    const float* bc = (const float*)d_in[11];

    float* out = (float*)d_out;                 // [N*D] output, then [N] change scores

    unsigned short* xb  = (unsigned short*)d_ws;
    unsigned short* Qb  = xb  + (size_t)NN * DD;
    unsigned short* Kb2 = Qb  + (size_t)NN * DD;
    unsigned short* Vtb = Kb2 + (size_t)NN * DD;   // transposed [b][h*64+d][s]
    unsigned short* Abf = Vtb + (size_t)NN * DD;
    unsigned short* Wqb = Abf + (size_t)NN * DD;
    unsigned short* Wkb = Wqb + (size_t)DD * DD;
    unsigned short* Wvb = Wkb + (size_t)DD * DD;
    unsigned short* Wob = Wvb + (size_t)DD * DD;
    int* lo = (int*)(Wob + (size_t)DD * DD);
    int* hi = lo + NN;

    // fused converts + band bounds (one launch)
    cvt_band<<<12320, 256, 0, stream>>>(x, Wq, Wk, Wv, Wo, ts,
                                        xb, Wqb, Wkb, Wvb, Wob, lo, hi);

    dim3 g(NN / 128, DD / 128);
    gemm_bf16<1><<<g, 256, 0, stream>>>(xb, Wqb, bq, Qb,  NN, DD, DD, SCALE2);
    gemm_bf16<1><<<g, 256, 0, stream>>>(xb, Wkb, bk, Kb2, NN, DD, DD, 1.0f);
    gemm_bf16<2><<<g, 256, 0, stream>>>(xb, Wvb, bv, Vtb, NN, DD, DD, 1.0f);
    attn_mfma<<<BB * HH * (SS / 64), 256, 0, stream>>>(Qb, Kb2, Vtb, ts, lo, hi, Abf);
    gemm_bf16<0><<<g, 256, 0, stream>>>(Abf, Wob, bo, out, NN, DD, DD, 1.0f);
    change_kernel<<<NN / 4, 256, 0, stream>>>(out, Wc, bc, out + (size_t)NN * DD);
}